// Round 7
// baseline (369.247 us; speedup 1.0000x reference)
//
#include <hip/hip_runtime.h>
#include <cfloat>
#include <cstddef>

// VQEmbeddingEMA inference forward — R6 arithmetic + m-split (2x wave count).
// x:   [B=32, N*D=512, L=1024] f32
// emb: [N=8, M=512, D=64] f32
// out: quantized_st [B,512,L] (16777216 f32) ++ loss (1) ++ perplexity (1)

#define N_G   8
#define M_CB  512
#define D_DIM 64
#define B_SZ  32
#define L_SEQ 1024
#define TOKENS (N_G * B_SZ * L_SEQ)                     // 262144
#define OUT_ELEMS ((size_t)B_SZ * N_G * D_DIM * L_SEQ)  // 16777216
#define MARGIN 2560
#define NLOSS 64

typedef _Float16 f16x8 __attribute__((ext_vector_type(8)));
typedef float    f32x4 __attribute__((ext_vector_type(4)));

// ---------------- workspace layout ----------------
//   [0,       524288)  e_f16  : codebook as f16, scaled by -2:  [n][m][d]
//   [524288,  540672)  e2p    : 1.0f + ||e||^2   (prescreen C-init table)
//   [540672,  557056)  e2raw  : ||e||^2          (exact fp32 rescore table)
//   [557056,  573440)  counts : int histogram [n][m]
//   [573440,  573696)  lossAcc: float[64]
#define EF_OFF   0
#define E2P_OFF  524288
#define E2R_OFF  540672
#define CNT_OFF  557056
#define LOSS_OFF 573440

__global__ void vq_ef16_kernel(const float* __restrict__ emb, unsigned int* __restrict__ ef) {
    int i = blockIdx.x * blockDim.x + threadIdx.x;    // handles 2 elements
    if (i < N_G * M_CB * D_DIM / 2) {
        float2 v = reinterpret_cast<const float2*>(emb)[i];
        _Float16 h0 = (_Float16)(-2.0f * v.x);
        _Float16 h1 = (_Float16)(-2.0f * v.y);
        unsigned int u0 = (unsigned int)__builtin_bit_cast(unsigned short, h0);
        unsigned int u1 = (unsigned int)__builtin_bit_cast(unsigned short, h1);
        ef[i] = u0 | (u1 << 16);
    }
}

__global__ void vq_e2_kernel(const float* __restrict__ emb,
                             float* __restrict__ e2raw,
                             float* __restrict__ e2p) {
    int i = blockIdx.x * blockDim.x + threadIdx.x;
    if (i < N_G * M_CB) {
        const float* e = emb + (size_t)i * D_DIM;
        float s0 = 0.f, s1 = 0.f, s2 = 0.f, s3 = 0.f;
        #pragma unroll
        for (int d = 0; d < D_DIM; d += 4) {
            s0 = fmaf(e[d+0], e[d+0], s0);
            s1 = fmaf(e[d+1], e[d+1], s1);
            s2 = fmaf(e[d+2], e[d+2], s2);
            s3 = fmaf(e[d+3], e[d+3], s3);
        }
        float s = (s0 + s1) + (s2 + s3);
        e2raw[i] = s;
        e2p[i] = 1.0f + s;
    }
}

// ---------------- MFMA main kernel (m-split) ----------------
// Grid 2048. Block = 256 thr = 4 waves = 2 token-pairs x 2 m-halves; 128 tokens/block.
// Wave (pr,hf): prescreen m-half hf (16 tiles) for token-pair pr's 64 tokens
// (4 strips of 16). Candidates merge via LDS; hf==0 wave runs exact epilogue
// (streaming x from cache — no xv[] register array).
__global__ __launch_bounds__(256, 4)
void vq_mfma_kernel(const float* __restrict__ x,
                    const float* __restrict__ emb,
                    const unsigned short* __restrict__ ef16,
                    const float* __restrict__ e2raw,
                    const float* __restrict__ e2p,
                    float* __restrict__ out,
                    int* __restrict__ counts,
                    float* __restrict__ lossAcc) {
    __shared__ int hist[M_CB];
    __shared__ int cands[2][4][16][16];  // [pair][strip][cc][hf*8 + kl*2 + t]

    const int tid  = threadIdx.x;
    hist[tid] = 0;
    hist[tid + 256] = 0;

    const int lane = tid & 63;
    const int wv   = tid >> 6;
    const int pr   = wv >> 1;            // token pair within block
    const int hf   = wv & 1;             // m half scanned by this wave
    const int cc   = lane & 15;          // token col within strip / A-row (m)
    const int kl   = lane >> 4;          // k-chunk id / D row-group
    const int kl4  = kl << 2;

    const int bb  = blockIdx.x;          // [0,2048)
    const int n   = bb >> 8;
    const int rem = bb & 255;
    const int b   = rem >> 3;
    const int l0  = ((rem & 7) << 7) + (pr << 6);   // wave's token base

    const float* __restrict__ xg = x + (size_t)(b * N_G + n) * D_DIM * L_SEQ;
    const unsigned short* __restrict__ eh = ef16 + ((size_t)n * M_CB + hf * 256) * D_DIM;
    const float* __restrict__ e2h = e2p + n * M_CB + hf * 256;

    // ---- load X fragments (global -> f16), accumulate Sum(x^2) on the fly ----
    // Wave's lanes collectively read its 64 tokens x 64 dims exactly once.
    f16x8 xf[4][2];
    float x2p = 0.f;
    #pragma unroll
    for (int s = 0; s < 4; ++s) {
        const int tok = l0 + s * 16 + cc;
        #pragma unroll
        for (int kc = 0; kc < 2; ++kc) {
            const int dbase = kc * 32 + kl * 8;
            f16x8 v;
            #pragma unroll
            for (int j = 0; j < 8; ++j) {
                const float xs = xg[(size_t)(dbase + j) * L_SEQ + tok];
                x2p = fmaf(xs, xs, x2p);
                v[j] = (_Float16)xs;
            }
            xf[s][kc] = v;
        }
    }

    int t1[4], t2[4];
    #pragma unroll
    for (int s = 0; s < 4; ++s) { t1[s] = 0x7FFFFFFF; t2[s] = 0x7FFFFFFF; }

    // ---- prescreen: 16 m-tiles (this wave's half); loads in-loop ----
    #pragma unroll 2
    for (int mt = 0; mt < 16; ++mt) {
        const unsigned short* erow = eh + (size_t)(mt * 16 + cc) * D_DIM + kl * 8;
        const f16x8 ea0 = *reinterpret_cast<const f16x8*>(erow);
        const f16x8 ea1 = *reinterpret_cast<const f16x8*>(erow + 32);
        const f32x4 ce2 = *reinterpret_cast<const f32x4*>(e2h + mt * 16 + kl4);
        const int mb = hf * 256 + mt * 16 + kl4;   // global m base for lane's D rows

        #pragma unroll
        for (int s = 0; s < 4; ++s) {
            f32x4 dacc = __builtin_amdgcn_mfma_f32_16x16x32_f16(ea0, xf[s][0], ce2,  0, 0, 0);
            dacc       = __builtin_amdgcn_mfma_f32_16x16x32_f16(ea1, xf[s][1], dacc, 0, 0, 0);
            // dacc[r] = 1 + e2 - 2*dot > 0: int-monotone after mask|idx pack
            const int p0 = (__float_as_int(dacc[0]) & ~511) | (mb + 0);
            const int p1 = (__float_as_int(dacc[1]) & ~511) | (mb + 1);
            const int p2 = (__float_as_int(dacc[2]) & ~511) | (mb + 2);
            const int p3 = (__float_as_int(dacc[3]) & ~511) | (mb + 3);
            int mn = min(p0, p1), mx = max(p0, p1);
            t2[s] = min(t2[s], max(min(t1[s], mx), mn));   // med3(t1,p0,p1)
            t1[s] = min(t1[s], mn);
            mn = min(p2, p3); mx = max(p2, p3);
            t2[s] = min(t2[s], max(min(t1[s], mx), mn));
            t1[s] = min(t1[s], mn);
        }
    }

    // ---- hand candidates to owning wave via LDS ----
    #pragma unroll
    for (int s = 0; s < 4; ++s) {
        cands[pr][s][cc][hf * 8 + kl * 2 + 0] = t1[s];
        cands[pr][s][cc][hf * 8 + kl * 2 + 1] = t2[s];
    }
    __syncthreads();

    // ---- epilogue: hf==0 wave owns its pair's 64 tokens (1 lane = 1 token) ----
    if (hf == 0) {
        const int tok = l0 + lane;       // lane's strip = lane>>4 (== kl), col = lane&15
        int cd[16];
        #pragma unroll
        for (int j = 0; j < 16; ++j) cd[j] = cands[pr][kl][cc][j];
        int pmin = cd[0];
        #pragma unroll
        for (int j = 1; j < 16; ++j) pmin = min(pmin, cd[j]);

        const float* __restrict__ eg  = emb + (size_t)n * M_CB * D_DIM;
        const float* __restrict__ e2g = e2raw + n * M_CB;

        // exact fp32 rescore of near-minimal candidates (streaming x, single path)
        float best1 = FLT_MAX, best2 = FLT_MAX;
        int   idx1  = 0x7FFFFFFF, idx2 = 0x7FFFFFFF;
        for (int j = 0; j < 16; ++j) {
            if (cd[j] - pmin <= MARGIN) {
                const int m = cd[j] & 511;
                const float4* em4 = reinterpret_cast<const float4*>(eg + (size_t)m * D_DIM);
                float a0 = 0.f, a1 = 0.f, a2 = 0.f, a3 = 0.f;
                #pragma unroll
                for (int q = 0; q < 16; ++q) {
                    const float4 e4 = em4[q];
                    a0 = fmaf(xg[(size_t)(q*4+0) * L_SEQ + tok], e4.x, a0);
                    a1 = fmaf(xg[(size_t)(q*4+1) * L_SEQ + tok], e4.y, a1);
                    a2 = fmaf(xg[(size_t)(q*4+2) * L_SEQ + tok], e4.z, a2);
                    a3 = fmaf(xg[(size_t)(q*4+3) * L_SEQ + tok], e4.w, a3);
                }
                const float dist = fmaf(-2.f, (a0 + a1) + (a2 + a3), e2g[m]);
                if (dist < best1 || (dist == best1 && m < idx1)) {
                    best2 = best1; idx2 = idx1; best1 = dist; idx1 = m;
                } else if (dist < best2 || (dist == best2 && m < idx2)) {
                    best2 = dist; idx2 = m;
                }
            }
        }

        // fp64 rescue for near-ties (streaming x; validated semantics)
        if (best2 - best1 < 1e-4f) {
            const float* eA = eg + (size_t)idx1 * D_DIM;
            const float* eB = eg + (size_t)idx2 * D_DIM;
            double dA = 0.0, dB = 0.0;
            #pragma unroll
            for (int d = 0; d < D_DIM; ++d) {
                const double xd = (double)xg[(size_t)d * L_SEQ + tok];
                const double da = xd - (double)eA[d];
                const double db = xd - (double)eB[d];
                dA = fma(da, da, dA);
                dB = fma(db, db, dB);
            }
            if (dB < dA || (dB == dA && idx2 < idx1)) { idx1 = idx2; best1 = best2; }
        }

        // out = q; loss = Sum(x^2) + best dist; histogram
        const size_t obase = (size_t)(b * N_G + n) * D_DIM * L_SEQ + (size_t)tok;
        const float* __restrict__ ebest = eg + (size_t)idx1 * D_DIM;
        #pragma unroll
        for (int d = 0; d < D_DIM; d += 4) {
            const float4 qv = *reinterpret_cast<const float4*>(ebest + d);
            out[obase + (size_t)(d+0) * L_SEQ] = qv.x;
            out[obase + (size_t)(d+1) * L_SEQ] = qv.y;
            out[obase + (size_t)(d+2) * L_SEQ] = qv.z;
            out[obase + (size_t)(d+3) * L_SEQ] = qv.w;
        }

        float sq = x2p + best1;
        #pragma unroll
        for (int off = 32; off > 0; off >>= 1)
            sq += __shfl_down(sq, off, 64);
        if (lane == 0)
            atomicAdd(&lossAcc[bb & (NLOSS - 1)], sq);

        atomicAdd(&hist[idx1], 1);
    }
    __syncthreads();
    {
        const int base = n * M_CB;
        int c0 = hist[tid];
        int c1 = hist[tid + 256];
        if (c0) atomicAdd(&counts[base + tid], c0);
        if (c1) atomicAdd(&counts[base + tid + 256], c1);
    }
}

__global__ void vq_finalize_kernel(const int* __restrict__ counts,
                                   const float* __restrict__ lossAcc,
                                   float* __restrict__ outTail) {
    __shared__ float red[256];
    const int tid = threadIdx.x;
    float perp = 0.f;
    for (int n = 0; n < N_G; ++n) {
        float h = 0.f;
        for (int m = tid; m < M_CB; m += 256) {
            const float p = (float)counts[n * M_CB + m] * (1.0f / (B_SZ * L_SEQ));
            h += p * logf(p + 1e-10f);
        }
        red[tid] = h;
        __syncthreads();
        #pragma unroll
        for (int s = 128; s > 0; s >>= 1) {
            if (tid < s) red[tid] += red[tid + s];
            __syncthreads();
        }
        if (tid == 0) perp += expf(-red[0]);
        __syncthreads();
    }
    if (tid == 0) {
        float ls = 0.f;
        for (int j = 0; j < NLOSS; ++j) ls += lossAcc[j];
        outTail[0] = 0.25f * (ls / (float)OUT_ELEMS);
        outTail[1] = perp;
    }
}

extern "C" void kernel_launch(void* const* d_in, const int* in_sizes, int n_in,
                              void* d_out, int out_size, void* d_ws, size_t ws_size,
                              hipStream_t stream) {
    const float* x   = (const float*)d_in[0];
    const float* emb = (const float*)d_in[1];
    float* out = (float*)d_out;
    char*  ws  = (char*)d_ws;

    unsigned int* ef16u  = (unsigned int*)(ws + EF_OFF);
    float* e2p    = (float*)(ws + E2P_OFF);
    float* e2r    = (float*)(ws + E2R_OFF);
    int*   counts = (int*)(ws + CNT_OFF);
    float* lossA  = (float*)(ws + LOSS_OFF);

    hipMemsetAsync(ws + CNT_OFF, 0, N_G * M_CB * 4 + NLOSS * 4, stream);
    vq_ef16_kernel<<<(N_G * M_CB * D_DIM / 2 + 255) / 256, 256, 0, stream>>>(emb, ef16u);
    vq_e2_kernel<<<(N_G * M_CB + 255) / 256, 256, 0, stream>>>(emb, e2r, e2p);
    vq_mfma_kernel<<<TOKENS / 128, 256, 0, stream>>>(
        x, emb, (const unsigned short*)ef16u, e2r, e2p, out, counts, lossA);
    vq_finalize_kernel<<<1, 256, 0, stream>>>(counts, lossA, out + OUT_ELEMS);
}

// Round 8
// 307.218 us; speedup vs baseline: 1.2019x; 1.2019x over previous
//
#include <hip/hip_runtime.h>
#include <cfloat>
#include <cstddef>

// VQEmbeddingEMA inference forward — m-split MFMA prescreen + margin-gated rare rescore.
// x:   [B=32, N*D=512, L=1024] f32
// emb: [N=8, M=512, D=64] f32
// out: quantized_st [B,512,L] (16777216 f32) ++ loss (1) ++ perplexity (1)

#define N_G   8
#define M_CB  512
#define D_DIM 64
#define B_SZ  32
#define L_SEQ 1024
#define TOKENS (N_G * B_SZ * L_SEQ)                     // 262144
#define OUT_ELEMS ((size_t)B_SZ * N_G * D_DIM * L_SEQ)  // 16777216
// Prescreen worst-case error: f16 dot err (<3e-4) + 9-bit key trunc (6.1e-5) < 3.6e-4.
// MARGIN = 4096 ulps @ exp(1.0) = 4.9e-4 > worst case -> accept-without-rescore is exact.
#define MARGIN 4096
#define NLOSS 64

typedef _Float16 f16x8 __attribute__((ext_vector_type(8)));
typedef float    f32x4 __attribute__((ext_vector_type(4)));

// ---------------- workspace layout ----------------
//   [0,       524288)  e_f16  : codebook as f16, scaled by -2:  [n][m][d]
//   [524288,  540672)  e2p    : 1.0f + ||e||^2   (prescreen C-init table)
//   [540672,  557056)  e2raw  : ||e||^2          (exact fp32 rescore table)
//   [557056,  573440)  counts : int histogram [n][m]
//   [573440,  573696)  lossAcc: float[64]
#define EF_OFF   0
#define E2P_OFF  524288
#define E2R_OFF  540672
#define CNT_OFF  557056
#define LOSS_OFF 573440

__global__ void vq_ef16_kernel(const float* __restrict__ emb, unsigned int* __restrict__ ef) {
    int i = blockIdx.x * blockDim.x + threadIdx.x;    // handles 2 elements
    if (i < N_G * M_CB * D_DIM / 2) {
        float2 v = reinterpret_cast<const float2*>(emb)[i];
        _Float16 h0 = (_Float16)(-2.0f * v.x);
        _Float16 h1 = (_Float16)(-2.0f * v.y);
        unsigned int u0 = (unsigned int)__builtin_bit_cast(unsigned short, h0);
        unsigned int u1 = (unsigned int)__builtin_bit_cast(unsigned short, h1);
        ef[i] = u0 | (u1 << 16);
    }
}

__global__ void vq_e2_kernel(const float* __restrict__ emb,
                             float* __restrict__ e2raw,
                             float* __restrict__ e2p) {
    int i = blockIdx.x * blockDim.x + threadIdx.x;
    if (i < N_G * M_CB) {
        const float* e = emb + (size_t)i * D_DIM;
        float s0 = 0.f, s1 = 0.f, s2 = 0.f, s3 = 0.f;
        #pragma unroll
        for (int d = 0; d < D_DIM; d += 4) {
            s0 = fmaf(e[d+0], e[d+0], s0);
            s1 = fmaf(e[d+1], e[d+1], s1);
            s2 = fmaf(e[d+2], e[d+2], s2);
            s3 = fmaf(e[d+3], e[d+3], s3);
        }
        float s = (s0 + s1) + (s2 + s3);
        e2raw[i] = s;
        e2p[i] = 1.0f + s;
    }
}

// ---------------- MFMA main kernel (m-split, margin-gated epilogue) ----------------
// Grid 2048. Block = 256 thr = 4 waves = 2 token-pairs x 2 m-halves; 128 tokens/block.
// Wave (pr,hf): prescreen m-half hf (16 tiles) for token-pair pr's 64 tokens.
// Candidates merge via LDS; hf==0 wave: accept prescreen argmin if 2nd-best is
// > MARGIN away (exact by error bound); else rare exact fp32/fp64 rescue (~5%).
__global__ __launch_bounds__(256, 4)
void vq_mfma_kernel(const float* __restrict__ x,
                    const float* __restrict__ emb,
                    const unsigned short* __restrict__ ef16,
                    const float* __restrict__ e2raw,
                    const float* __restrict__ e2p,
                    float* __restrict__ out,
                    int* __restrict__ counts,
                    float* __restrict__ lossAcc) {
    __shared__ int hist[M_CB];
    __shared__ int cands[2][4][16][16];  // [pair][strip][cc][hf*8 + kl*2 + t]

    const int tid  = threadIdx.x;
    hist[tid] = 0;
    hist[tid + 256] = 0;

    const int lane = tid & 63;
    const int wv   = tid >> 6;
    const int pr   = wv >> 1;            // token pair within block
    const int hf   = wv & 1;             // m half scanned by this wave
    const int cc   = lane & 15;          // token col within strip / A-row (m)
    const int kl   = lane >> 4;          // k-chunk id / D row-group
    const int kl4  = kl << 2;

    const int bb  = blockIdx.x;          // [0,2048)
    const int n   = bb >> 8;
    const int rem = bb & 255;
    const int b   = rem >> 3;
    const int l0  = ((rem & 7) << 7) + (pr << 6);   // wave's token base

    const float* __restrict__ xg = x + (size_t)(b * N_G + n) * D_DIM * L_SEQ;
    const unsigned short* __restrict__ eh = ef16 + ((size_t)n * M_CB + hf * 256) * D_DIM;
    const float* __restrict__ e2h = e2p + n * M_CB + hf * 256;

    // ---- load X fragments (global -> f16), accumulate Sum(x^2) on the fly ----
    f16x8 xf[4][2];
    float x2p = 0.f;
    #pragma unroll
    for (int s = 0; s < 4; ++s) {
        const int tok = l0 + s * 16 + cc;
        #pragma unroll
        for (int kc = 0; kc < 2; ++kc) {
            const int dbase = kc * 32 + kl * 8;
            f16x8 v;
            #pragma unroll
            for (int j = 0; j < 8; ++j) {
                const float xs = xg[(size_t)(dbase + j) * L_SEQ + tok];
                x2p = fmaf(xs, xs, x2p);
                v[j] = (_Float16)xs;
            }
            xf[s][kc] = v;
        }
    }

    int t1[4], t2[4];
    #pragma unroll
    for (int s = 0; s < 4; ++s) { t1[s] = 0x7FFFFFFF; t2[s] = 0x7FFFFFFF; }

    // ---- prescreen: 16 m-tiles (this wave's half); loads in-loop ----
    #pragma unroll 2
    for (int mt = 0; mt < 16; ++mt) {
        const unsigned short* erow = eh + (size_t)(mt * 16 + cc) * D_DIM + kl * 8;
        const f16x8 ea0 = *reinterpret_cast<const f16x8*>(erow);
        const f16x8 ea1 = *reinterpret_cast<const f16x8*>(erow + 32);
        const f32x4 ce2 = *reinterpret_cast<const f32x4*>(e2h + mt * 16 + kl4);
        const int mb = hf * 256 + mt * 16 + kl4;   // global m base for lane's D rows

        #pragma unroll
        for (int s = 0; s < 4; ++s) {
            f32x4 dacc = __builtin_amdgcn_mfma_f32_16x16x32_f16(ea0, xf[s][0], ce2,  0, 0, 0);
            dacc       = __builtin_amdgcn_mfma_f32_16x16x32_f16(ea1, xf[s][1], dacc, 0, 0, 0);
            // dacc[r] = 1 + e2 - 2*dot in ~(0.74,1.26): int-monotone after mask|idx pack
            const int p0 = (__float_as_int(dacc[0]) & ~511) | (mb + 0);
            const int p1 = (__float_as_int(dacc[1]) & ~511) | (mb + 1);
            const int p2 = (__float_as_int(dacc[2]) & ~511) | (mb + 2);
            const int p3 = (__float_as_int(dacc[3]) & ~511) | (mb + 3);
            int mn = min(p0, p1), mx = max(p0, p1);
            t2[s] = min(t2[s], max(min(t1[s], mx), mn));   // med3(t1,p0,p1)
            t1[s] = min(t1[s], mn);
            mn = min(p2, p3); mx = max(p2, p3);
            t2[s] = min(t2[s], max(min(t1[s], mx), mn));
            t1[s] = min(t1[s], mn);
        }
    }

    // ---- hand candidates to owning wave via LDS ----
    #pragma unroll
    for (int s = 0; s < 4; ++s) {
        cands[pr][s][cc][hf * 8 + kl * 2 + 0] = t1[s];
        cands[pr][s][cc][hf * 8 + kl * 2 + 1] = t2[s];
    }
    __syncthreads();

    // ---- epilogue: hf==0 wave owns its pair's 64 tokens (1 lane = 1 token) ----
    if (hf == 0) {
        const int tok = l0 + lane;       // lane's strip = lane>>4 (== kl), col = lane&15
        int cd[16];
        #pragma unroll
        for (int j = 0; j < 16; ++j) cd[j] = cands[pr][kl][cc][j];
        int pmin = cd[0];
        #pragma unroll
        for (int j = 1; j < 16; ++j) pmin = min(pmin, cd[j]);
        int t2u = 0x7FFFFFFF;
        #pragma unroll
        for (int j = 0; j < 16; ++j) {
            const int v = cd[j];
            t2u = min(t2u, (v == pmin) ? 0x7FFFFFFF : v);
        }

        const float* __restrict__ eg  = emb + (size_t)n * M_CB * D_DIM;
        const float* __restrict__ e2g = e2raw + n * M_CB;

        // fast path (>95% of tokens): 2nd-best out of margin -> prescreen argmin
        // is exact; loss dist from prescreen key (err <= 3.6e-4, negligible in mean)
        int   idx1  = pmin & 511;
        float best1 = __int_as_float(pmin & ~511) - 1.0f;

        if (t2u - pmin <= MARGIN) {
            // rare exact rescue: fp32 rescore of all within-margin candidates
            float b1 = FLT_MAX, b2 = FLT_MAX;
            int   i1 = 0x7FFFFFFF, i2 = 0x7FFFFFFF;
            for (int j = 0; j < 16; ++j) {
                if (cd[j] - pmin <= MARGIN) {
                    const int m = cd[j] & 511;
                    const float4* em4 = reinterpret_cast<const float4*>(eg + (size_t)m * D_DIM);
                    float a0 = 0.f, a1 = 0.f, a2 = 0.f, a3 = 0.f;
                    #pragma unroll
                    for (int q = 0; q < 16; ++q) {
                        const float4 e4 = em4[q];
                        a0 = fmaf(xg[(size_t)(q*4+0) * L_SEQ + tok], e4.x, a0);
                        a1 = fmaf(xg[(size_t)(q*4+1) * L_SEQ + tok], e4.y, a1);
                        a2 = fmaf(xg[(size_t)(q*4+2) * L_SEQ + tok], e4.z, a2);
                        a3 = fmaf(xg[(size_t)(q*4+3) * L_SEQ + tok], e4.w, a3);
                    }
                    const float dist = fmaf(-2.f, (a0 + a1) + (a2 + a3), e2g[m]);
                    if (dist < b1 || (dist == b1 && m < i1)) {
                        b2 = b1; i2 = i1; b1 = dist; i1 = m;
                    } else if (dist < b2 || (dist == b2 && m < i2)) {
                        b2 = dist; i2 = m;
                    }
                }
            }
            // fp64 rescue for near-ties (validated semantics)
            if (b2 - b1 < 1e-4f) {
                const float* eA = eg + (size_t)i1 * D_DIM;
                const float* eB = eg + (size_t)i2 * D_DIM;
                double dA = 0.0, dB = 0.0;
                #pragma unroll
                for (int d = 0; d < D_DIM; ++d) {
                    const double xd = (double)xg[(size_t)d * L_SEQ + tok];
                    const double da = xd - (double)eA[d];
                    const double db = xd - (double)eB[d];
                    dA = fma(da, da, dA);
                    dB = fma(db, db, dB);
                }
                if (dB < dA || (dB == dA && i2 < i1)) { i1 = i2; b1 = b2; }
            }
            idx1 = i1;
            best1 = b1;
        }

        // out = q; loss = Sum(x^2) + best dist; histogram
        const size_t obase = (size_t)(b * N_G + n) * D_DIM * L_SEQ + (size_t)tok;
        const float* __restrict__ ebest = eg + (size_t)idx1 * D_DIM;
        #pragma unroll
        for (int d = 0; d < D_DIM; d += 4) {
            const float4 qv = *reinterpret_cast<const float4*>(ebest + d);
            out[obase + (size_t)(d+0) * L_SEQ] = qv.x;
            out[obase + (size_t)(d+1) * L_SEQ] = qv.y;
            out[obase + (size_t)(d+2) * L_SEQ] = qv.z;
            out[obase + (size_t)(d+3) * L_SEQ] = qv.w;
        }

        float sq = x2p + best1;
        #pragma unroll
        for (int off = 32; off > 0; off >>= 1)
            sq += __shfl_down(sq, off, 64);
        if (lane == 0)
            atomicAdd(&lossAcc[bb & (NLOSS - 1)], sq);

        atomicAdd(&hist[idx1], 1);
    }
    __syncthreads();
    {
        const int base = n * M_CB;
        int c0 = hist[tid];
        int c1 = hist[tid + 256];
        if (c0) atomicAdd(&counts[base + tid], c0);
        if (c1) atomicAdd(&counts[base + tid + 256], c1);
    }
}

__global__ void vq_finalize_kernel(const int* __restrict__ counts,
                                   const float* __restrict__ lossAcc,
                                   float* __restrict__ outTail) {
    __shared__ float red[256];
    const int tid = threadIdx.x;
    float perp = 0.f;
    for (int n = 0; n < N_G; ++n) {
        float h = 0.f;
        for (int m = tid; m < M_CB; m += 256) {
            const float p = (float)counts[n * M_CB + m] * (1.0f / (B_SZ * L_SEQ));
            h += p * logf(p + 1e-10f);
        }
        red[tid] = h;
        __syncthreads();
        #pragma unroll
        for (int s = 128; s > 0; s >>= 1) {
            if (tid < s) red[tid] += red[tid + s];
            __syncthreads();
        }
        if (tid == 0) perp += expf(-red[0]);
        __syncthreads();
    }
    if (tid == 0) {
        float ls = 0.f;
        for (int j = 0; j < NLOSS; ++j) ls += lossAcc[j];
        outTail[0] = 0.25f * (ls / (float)OUT_ELEMS);
        outTail[1] = perp;
    }
}

extern "C" void kernel_launch(void* const* d_in, const int* in_sizes, int n_in,
                              void* d_out, int out_size, void* d_ws, size_t ws_size,
                              hipStream_t stream) {
    const float* x   = (const float*)d_in[0];
    const float* emb = (const float*)d_in[1];
    float* out = (float*)d_out;
    char*  ws  = (char*)d_ws;

    unsigned int* ef16u  = (unsigned int*)(ws + EF_OFF);
    float* e2p    = (float*)(ws + E2P_OFF);
    float* e2r    = (float*)(ws + E2R_OFF);
    int*   counts = (int*)(ws + CNT_OFF);
    float* lossA  = (float*)(ws + LOSS_OFF);

    hipMemsetAsync(ws + CNT_OFF, 0, N_G * M_CB * 4 + NLOSS * 4, stream);
    vq_ef16_kernel<<<(N_G * M_CB * D_DIM / 2 + 255) / 256, 256, 0, stream>>>(emb, ef16u);
    vq_e2_kernel<<<(N_G * M_CB + 255) / 256, 256, 0, stream>>>(emb, e2r, e2p);
    vq_mfma_kernel<<<TOKENS / 128, 256, 0, stream>>>(
        x, emb, (const unsigned short*)ef16u, e2r, e2p, out, counts, lossA);
    vq_finalize_kernel<<<1, 256, 0, stream>>>(counts, lossA, out + OUT_ELEMS);
}

// Round 9
// 161.603 us; speedup vs baseline: 2.2849x; 1.9011x over previous
//
#include <hip/hip_runtime.h>
#include <cfloat>
#include <cstddef>

// VQEmbeddingEMA inference forward — R6 arithmetic, 32 tokens/wave (2x TLP).
// x:   [B=32, N*D=512, L=1024] f32
// emb: [N=8, M=512, D=64] f32
// out: quantized_st [B,512,L] (16777216 f32) ++ loss (1) ++ perplexity (1)

#define N_G   8
#define M_CB  512
#define D_DIM 64
#define B_SZ  32
#define L_SEQ 1024
#define TOKENS (N_G * B_SZ * L_SEQ)                     // 262144
#define OUT_ELEMS ((size_t)B_SZ * N_G * D_DIM * L_SEQ)  // 16777216
#define MARGIN 2560
#define NLOSS 64

typedef _Float16 f16x8 __attribute__((ext_vector_type(8)));
typedef float    f32x4 __attribute__((ext_vector_type(4)));

// ---------------- workspace layout ----------------
//   [0,       524288)  e_f16  : codebook as f16, scaled by -2:  [n][m][d]
//   [524288,  540672)  e2p    : 1.0f + ||e||^2   (prescreen C-init table)
//   [540672,  557056)  e2raw  : ||e||^2          (exact fp32 rescore table)
//   [557056,  573440)  counts : int histogram [n][m]
//   [573440,  573696)  lossAcc: float[64]
#define EF_OFF   0
#define E2P_OFF  524288
#define E2R_OFF  540672
#define CNT_OFF  557056
#define LOSS_OFF 573440

__global__ void vq_ef16_kernel(const float* __restrict__ emb, unsigned int* __restrict__ ef) {
    int i = blockIdx.x * blockDim.x + threadIdx.x;    // handles 2 elements
    if (i < N_G * M_CB * D_DIM / 2) {
        float2 v = reinterpret_cast<const float2*>(emb)[i];
        _Float16 h0 = (_Float16)(-2.0f * v.x);
        _Float16 h1 = (_Float16)(-2.0f * v.y);
        unsigned int u0 = (unsigned int)__builtin_bit_cast(unsigned short, h0);
        unsigned int u1 = (unsigned int)__builtin_bit_cast(unsigned short, h1);
        ef[i] = u0 | (u1 << 16);
    }
}

__global__ void vq_e2_kernel(const float* __restrict__ emb,
                             float* __restrict__ e2raw,
                             float* __restrict__ e2p) {
    int i = blockIdx.x * blockDim.x + threadIdx.x;
    if (i < N_G * M_CB) {
        const float* e = emb + (size_t)i * D_DIM;
        float s0 = 0.f, s1 = 0.f, s2 = 0.f, s3 = 0.f;
        #pragma unroll
        for (int d = 0; d < D_DIM; d += 4) {
            s0 = fmaf(e[d+0], e[d+0], s0);
            s1 = fmaf(e[d+1], e[d+1], s1);
            s2 = fmaf(e[d+2], e[d+2], s2);
            s3 = fmaf(e[d+3], e[d+3], s3);
        }
        float s = (s0 + s1) + (s2 + s3);
        e2raw[i] = s;
        e2p[i] = 1.0f + s;
    }
}

// ---------------- MFMA main kernel ----------------
// Grid 2048. Block = 256 thr = 4 waves; 128 tokens/block, 32 tokens/wave
// (2 strips of 16). Per strip: D[m 16][tok 16] = mfma(A=-2E, B=X, C=1+e2) x2 k.
// Epilogue (lanes 0-31, one lane per token): R6-validated register-xv rescore.
__global__ __launch_bounds__(256, 4)
void vq_mfma_kernel(const float* __restrict__ x,
                    const float* __restrict__ emb,
                    const unsigned short* __restrict__ ef16,
                    const float* __restrict__ e2raw,
                    const float* __restrict__ e2p,
                    float* __restrict__ out,
                    int* __restrict__ counts,
                    float* __restrict__ lossAcc) {
    __shared__ int hist[M_CB];
    __shared__ int cands[4][2][16][8];   // [wave][strip][col][4 lane-slots x top2]

    const int tid  = threadIdx.x;
    hist[tid] = 0;
    hist[tid + 256] = 0;

    const int lane = tid & 63;
    const int wv   = tid >> 6;
    const int cc   = lane & 15;          // token col within strip / A-row (m)
    const int kl   = lane >> 4;          // k-chunk id / D row-group
    const int kl4  = kl << 2;

    const int bb  = blockIdx.x;          // [0,2048)
    const int n   = bb >> 8;
    const int rem = bb & 255;
    const int b   = rem >> 3;
    const int l0  = ((rem & 7) << 7) + (wv << 5);   // wave's token base (32 tokens)

    const float* __restrict__ xg = x + (size_t)(b * N_G + n) * D_DIM * L_SEQ;
    const unsigned short* __restrict__ eg16 = ef16 + (size_t)n * M_CB * D_DIM;
    const float* __restrict__ e2pg = e2p + n * M_CB;

    // ---- load X fragments (global -> f16), accumulate Sum(x^2) on the fly ----
    f16x8 xf[2][2];
    float x2p = 0.f;
    #pragma unroll
    for (int s = 0; s < 2; ++s) {
        const int tok = l0 + s * 16 + cc;
        #pragma unroll
        for (int kc = 0; kc < 2; ++kc) {
            const int dbase = kc * 32 + kl * 8;
            f16x8 v;
            #pragma unroll
            for (int j = 0; j < 8; ++j) {
                const float xs = xg[(size_t)(dbase + j) * L_SEQ + tok];
                x2p = fmaf(xs, xs, x2p);
                v[j] = (_Float16)xs;
            }
            xf[s][kc] = v;
        }
    }

    int t1[2], t2[2];
    #pragma unroll
    for (int s = 0; s < 2; ++s) { t1[s] = 0x7FFFFFFF; t2[s] = 0x7FFFFFFF; }

    // ---- prescreen: 32 m-tiles; loads in-loop, compiler schedules ----
    #pragma unroll 2
    for (int mt = 0; mt < 32; ++mt) {
        const unsigned short* erow = eg16 + (size_t)(mt * 16 + cc) * D_DIM + kl * 8;
        const f16x8 ea0 = *reinterpret_cast<const f16x8*>(erow);
        const f16x8 ea1 = *reinterpret_cast<const f16x8*>(erow + 32);
        const f32x4 ce2 = *reinterpret_cast<const f32x4*>(e2pg + mt * 16 + kl4);
        const int mb = mt * 16 + kl4;    // m base for this lane's D rows

        #pragma unroll
        for (int s = 0; s < 2; ++s) {
            f32x4 dacc = __builtin_amdgcn_mfma_f32_16x16x32_f16(ea0, xf[s][0], ce2,  0, 0, 0);
            dacc       = __builtin_amdgcn_mfma_f32_16x16x32_f16(ea1, xf[s][1], dacc, 0, 0, 0);
            // dacc[r] = 1 + e2 - 2*dot > 0: int-monotone after mask|idx pack
            const int p0 = (__float_as_int(dacc[0]) & ~511) | (mb + 0);
            const int p1 = (__float_as_int(dacc[1]) & ~511) | (mb + 1);
            const int p2 = (__float_as_int(dacc[2]) & ~511) | (mb + 2);
            const int p3 = (__float_as_int(dacc[3]) & ~511) | (mb + 3);
            int mn = min(p0, p1), mx = max(p0, p1);
            t2[s] = min(t2[s], max(min(t1[s], mx), mn));   // med3(t1,p0,p1)
            t1[s] = min(t1[s], mn);
            mn = min(p2, p3); mx = max(p2, p3);
            t2[s] = min(t2[s], max(min(t1[s], mx), mn));
            t1[s] = min(t1[s], mn);
        }
    }

    // ---- hand candidates to owning lane via LDS ----
    #pragma unroll
    for (int s = 0; s < 2; ++s) {
        cands[wv][s][cc][kl * 2 + 0] = t1[s];
        cands[wv][s][cc][kl * 2 + 1] = t2[s];
    }
    __syncthreads();

    // ---- epilogue: lanes 0-31 own one token each (strip = lane>>4, col = lane&15) ----
    float bestd = 0.f;                   // lane's chosen distance (0 in idle lanes)
    if (lane < 32) {
        const int tok = l0 + lane;
        int cd[8];
        #pragma unroll
        for (int j = 0; j < 8; ++j) cd[j] = cands[wv][kl][cc][j];
        int pmin = cd[0];
        #pragma unroll
        for (int j = 1; j < 8; ++j) pmin = min(pmin, cd[j]);

        // reload this token's x column (fp32, coalesced, L2-hot)
        float xv[D_DIM];
        #pragma unroll
        for (int d = 0; d < D_DIM; ++d)
            xv[d] = xg[(size_t)d * L_SEQ + tok];

        // exact fp32 rescore of near-minimal candidates (R6 single masked path)
        const float* __restrict__ eg  = emb + (size_t)n * M_CB * D_DIM;
        const float* __restrict__ e2g = e2raw + n * M_CB;
        float best1 = FLT_MAX, best2 = FLT_MAX;
        int   idx1  = 0x7FFFFFFF, idx2 = 0x7FFFFFFF;
        for (int j = 0; j < 8; ++j) {
            if (cd[j] - pmin <= MARGIN) {
                const int m = cd[j] & 511;
                const float4* em4 = reinterpret_cast<const float4*>(eg + (size_t)m * D_DIM);
                float a0 = 0.f, a1 = 0.f, a2 = 0.f, a3 = 0.f;
                #pragma unroll
                for (int q = 0; q < 16; ++q) {
                    const float4 e4 = em4[q];
                    a0 = fmaf(xv[q*4+0], e4.x, a0);
                    a1 = fmaf(xv[q*4+1], e4.y, a1);
                    a2 = fmaf(xv[q*4+2], e4.z, a2);
                    a3 = fmaf(xv[q*4+3], e4.w, a3);
                }
                const float dist = fmaf(-2.f, (a0 + a1) + (a2 + a3), e2g[m]);
                if (dist < best1 || (dist == best1 && m < idx1)) {
                    best2 = best1; idx2 = idx1; best1 = dist; idx1 = m;
                } else if (dist < best2 || (dist == best2 && m < idx2)) {
                    best2 = dist; idx2 = m;
                }
            }
        }

        // fp64 rescue for near-ties (validated semantics)
        if (best2 - best1 < 1e-4f) {
            const float* eA = eg + (size_t)idx1 * D_DIM;
            const float* eB = eg + (size_t)idx2 * D_DIM;
            double dA = 0.0, dB = 0.0;
            #pragma unroll
            for (int d = 0; d < D_DIM; ++d) {
                const double da = (double)xv[d] - (double)eA[d];
                const double db = (double)xv[d] - (double)eB[d];
                dA = fma(da, da, dA);
                dB = fma(db, db, dB);
            }
            if (dB < dA || (dB == dA && idx2 < idx1)) { idx1 = idx2; best1 = best2; }
        }

        // out = q; histogram
        const size_t obase = (size_t)(b * N_G + n) * D_DIM * L_SEQ + (size_t)tok;
        const float* __restrict__ ebest = eg + (size_t)idx1 * D_DIM;
        #pragma unroll
        for (int d = 0; d < D_DIM; d += 4) {
            const float4 qv = *reinterpret_cast<const float4*>(ebest + d);
            out[obase + (size_t)(d+0) * L_SEQ] = qv.x;
            out[obase + (size_t)(d+1) * L_SEQ] = qv.y;
            out[obase + (size_t)(d+2) * L_SEQ] = qv.z;
            out[obase + (size_t)(d+3) * L_SEQ] = qv.w;
        }
        atomicAdd(&hist[idx1], 1);
        bestd = best1;
    }

    // ---- loss: full-wave reduction of Sum(x^2) + chosen distances ----
    float sq = x2p + bestd;
    #pragma unroll
    for (int off = 32; off > 0; off >>= 1)
        sq += __shfl_down(sq, off, 64);
    if (lane == 0)
        atomicAdd(&lossAcc[bb & (NLOSS - 1)], sq);

    __syncthreads();
    {
        const int base = n * M_CB;
        int c0 = hist[tid];
        int c1 = hist[tid + 256];
        if (c0) atomicAdd(&counts[base + tid], c0);
        if (c1) atomicAdd(&counts[base + tid + 256], c1);
    }
}

__global__ void vq_finalize_kernel(const int* __restrict__ counts,
                                   const float* __restrict__ lossAcc,
                                   float* __restrict__ outTail) {
    __shared__ float red[256];
    const int tid = threadIdx.x;
    float perp = 0.f;
    for (int n = 0; n < N_G; ++n) {
        float h = 0.f;
        for (int m = tid; m < M_CB; m += 256) {
            const float p = (float)counts[n * M_CB + m] * (1.0f / (B_SZ * L_SEQ));
            h += p * logf(p + 1e-10f);
        }
        red[tid] = h;
        __syncthreads();
        #pragma unroll
        for (int s = 128; s > 0; s >>= 1) {
            if (tid < s) red[tid] += red[tid + s];
            __syncthreads();
        }
        if (tid == 0) perp += expf(-red[0]);
        __syncthreads();
    }
    if (tid == 0) {
        float ls = 0.f;
        for (int j = 0; j < NLOSS; ++j) ls += lossAcc[j];
        outTail[0] = 0.25f * (ls / (float)OUT_ELEMS);
        outTail[1] = perp;
    }
}

extern "C" void kernel_launch(void* const* d_in, const int* in_sizes, int n_in,
                              void* d_out, int out_size, void* d_ws, size_t ws_size,
                              hipStream_t stream) {
    const float* x   = (const float*)d_in[0];
    const float* emb = (const float*)d_in[1];
    float* out = (float*)d_out;
    char*  ws  = (char*)d_ws;

    unsigned int* ef16u  = (unsigned int*)(ws + EF_OFF);
    float* e2p    = (float*)(ws + E2P_OFF);
    float* e2r    = (float*)(ws + E2R_OFF);
    int*   counts = (int*)(ws + CNT_OFF);
    float* lossA  = (float*)(ws + LOSS_OFF);

    hipMemsetAsync(ws + CNT_OFF, 0, N_G * M_CB * 4 + NLOSS * 4, stream);
    vq_ef16_kernel<<<(N_G * M_CB * D_DIM / 2 + 255) / 256, 256, 0, stream>>>(emb, ef16u);
    vq_e2_kernel<<<(N_G * M_CB + 255) / 256, 256, 0, stream>>>(emb, e2r, e2p);
    vq_mfma_kernel<<<TOKENS / 128, 256, 0, stream>>>(
        x, emb, (const unsigned short*)ef16u, e2r, e2p, out, counts, lossA);
    vq_finalize_kernel<<<1, 256, 0, stream>>>(counts, lossA, out + OUT_ELEMS);
}

// Round 10
// 95.693 us; speedup vs baseline: 3.8587x; 1.6888x over previous
//
#include <hip/hip_runtime.h>
#include <cfloat>
#include <cstddef>

// VQEmbeddingEMA inference forward — R6 frame + LDS-staged codebook (coalesced, padded).
// x:   [B=32, N*D=512, L=1024] f32
// emb: [N=8, M=512, D=64] f32
// out: quantized_st [B,512,L] (16777216 f32) ++ loss (1) ++ perplexity (1)

#define N_G   8
#define M_CB  512
#define D_DIM 64
#define B_SZ  32
#define L_SEQ 1024
#define TOKENS (N_G * B_SZ * L_SEQ)                     // 262144
#define OUT_ELEMS ((size_t)B_SZ * N_G * D_DIM * L_SEQ)  // 16777216
#define MARGIN 2560
#define NLOSS 64

typedef _Float16 f16x8 __attribute__((ext_vector_type(8)));
typedef float    f32x4 __attribute__((ext_vector_type(4)));

// ---------------- workspace layout ----------------
//   [0,       524288)  e_f16  : codebook as f16, scaled by -2:  [n][m][d]
//   [524288,  540672)  e2p    : 1.0f + ||e||^2   (prescreen C-init table)
//   [540672,  557056)  e2raw  : ||e||^2          (exact fp32 rescore table)
//   [557056,  573440)  counts : int histogram [n][m]
//   [573440,  573696)  lossAcc: float[64]
#define EF_OFF   0
#define E2P_OFF  524288
#define E2R_OFF  540672
#define CNT_OFF  557056
#define LOSS_OFF 573440

__global__ void vq_ef16_kernel(const float* __restrict__ emb, unsigned int* __restrict__ ef) {
    int i = blockIdx.x * blockDim.x + threadIdx.x;    // handles 2 elements
    if (i < N_G * M_CB * D_DIM / 2) {
        float2 v = reinterpret_cast<const float2*>(emb)[i];
        _Float16 h0 = (_Float16)(-2.0f * v.x);
        _Float16 h1 = (_Float16)(-2.0f * v.y);
        unsigned int u0 = (unsigned int)__builtin_bit_cast(unsigned short, h0);
        unsigned int u1 = (unsigned int)__builtin_bit_cast(unsigned short, h1);
        ef[i] = u0 | (u1 << 16);
    }
}

__global__ void vq_e2_kernel(const float* __restrict__ emb,
                             float* __restrict__ e2raw,
                             float* __restrict__ e2p) {
    int i = blockIdx.x * blockDim.x + threadIdx.x;
    if (i < N_G * M_CB) {
        const float* e = emb + (size_t)i * D_DIM;
        float s0 = 0.f, s1 = 0.f, s2 = 0.f, s3 = 0.f;
        #pragma unroll
        for (int d = 0; d < D_DIM; d += 4) {
            s0 = fmaf(e[d+0], e[d+0], s0);
            s1 = fmaf(e[d+1], e[d+1], s1);
            s2 = fmaf(e[d+2], e[d+2], s2);
            s3 = fmaf(e[d+3], e[d+3], s3);
        }
        float s = (s0 + s1) + (s2 + s3);
        e2raw[i] = s;
        e2p[i] = 1.0f + s;
    }
}

// ---------------- MFMA main kernel (R6 frame + LDS codebook staging) ----------------
// Block = 256 thr = 4 waves, 256 tokens (one (n,b) pair). Wave = 64 tokens,
// 4 strips of 16. Codebook staged in LDS: 8 chunks x 4 tiles (64 codes, 8 KB
// coalesced global read), padded rows [72 shorts] -> conflict-free ds ops.
__global__ __launch_bounds__(256, 4)
void vq_mfma_kernel(const float* __restrict__ x,
                    const float* __restrict__ emb,
                    const unsigned short* __restrict__ ef16,
                    const float* __restrict__ e2raw,
                    const float* __restrict__ e2p,
                    float* __restrict__ out,
                    int* __restrict__ counts,
                    float* __restrict__ lossAcc) {
    __shared__ int hist[M_CB];
    __shared__ int cands[4][4][16][8];   // [wave][strip][col][4 lane-slots x top2]
    __shared__ __align__(16) short ebuf[4 * 16 * 72];   // 4 tiles x 16 rows x 72 shorts (pad 8)

    const int tid  = threadIdx.x;
    hist[tid] = 0;
    hist[tid + 256] = 0;

    const int lane = tid & 63;
    const int wv   = tid >> 6;
    const int cc   = lane & 15;          // token col within strip / A-row (m)
    const int kl   = lane >> 4;          // k-chunk id / D row-group
    const int kl4  = kl << 2;

    const int bb  = blockIdx.x;          // [0,1024)
    const int n   = bb >> 7;
    const int rem = bb & 127;
    const int b   = rem >> 2;
    const int l0  = ((rem & 3) << 8) + (wv << 6);   // wave's token base

    const float* __restrict__ xg = x + (size_t)(b * N_G + n) * D_DIM * L_SEQ;
    const unsigned short* __restrict__ eg16 = ef16 + (size_t)n * M_CB * D_DIM;
    const float* __restrict__ e2pg = e2p + n * M_CB;

    // staging coords for this thread (chunk ids tid and tid+256 of 512 per outer)
    const int st_t0 = tid >> 7;          // tile 0/1
    const int st_r0 = (tid >> 3) & 15;   // row
    const int st_c0 = tid & 7;           // 16B col
    const int st_o0 = st_t0 * 1152 + st_r0 * 72 + st_c0 * 8;   // LDS short offset
    const int st_o1 = (st_t0 + 2) * 1152 + st_r0 * 72 + st_c0 * 8;

    // ---- load X fragments (global -> f16), accumulate Sum(x^2) on the fly ----
    f16x8 xf[4][2];
    float x2p = 0.f;
    #pragma unroll
    for (int s = 0; s < 4; ++s) {
        const int tok = l0 + s * 16 + cc;
        #pragma unroll
        for (int kc = 0; kc < 2; ++kc) {
            const int dbase = kc * 32 + kl * 8;
            f16x8 v;
            #pragma unroll
            for (int j = 0; j < 8; ++j) {
                const float xs = xg[(size_t)(dbase + j) * L_SEQ + tok];
                x2p = fmaf(xs, xs, x2p);
                v[j] = (_Float16)xs;
            }
            xf[s][kc] = v;
        }
    }

    int t1[4], t2[4];
    #pragma unroll
    for (int s = 0; s < 4; ++s) { t1[s] = 0x7FFFFFFF; t2[s] = 0x7FFFFFFF; }

    // ---- prescreen: 8 outer chunks x 4 m-tiles; codebook via LDS ----
    for (int outer = 0; outer < 8; ++outer) {
        // stage 4 tiles (64 codes, 8 KB) coalesced: chunk c -> global short c*8
        {
            const unsigned short* gsrc = eg16 + outer * 4096;
            const uint4 g0 = *reinterpret_cast<const uint4*>(gsrc + tid * 8);
            const uint4 g1 = *reinterpret_cast<const uint4*>(gsrc + 2048 + tid * 8);
            *reinterpret_cast<uint4*>(&ebuf[st_o0]) = g0;
            *reinterpret_cast<uint4*>(&ebuf[st_o1]) = g1;
        }
        __syncthreads();

        #pragma unroll
        for (int ml = 0; ml < 4; ++ml) {
            const short* erow = &ebuf[ml * 1152 + cc * 72 + kl * 8];
            const f16x8 ea0 = *reinterpret_cast<const f16x8*>(erow);
            const f16x8 ea1 = *reinterpret_cast<const f16x8*>(erow + 32);
            const int mt = outer * 4 + ml;
            const f32x4 ce2 = *reinterpret_cast<const f32x4*>(e2pg + mt * 16 + kl4);
            const int mb = mt * 16 + kl4;    // m base for this lane's D rows

            #pragma unroll
            for (int s = 0; s < 4; ++s) {
                f32x4 dacc = __builtin_amdgcn_mfma_f32_16x16x32_f16(ea0, xf[s][0], ce2,  0, 0, 0);
                dacc       = __builtin_amdgcn_mfma_f32_16x16x32_f16(ea1, xf[s][1], dacc, 0, 0, 0);
                // dacc[r] = 1 + e2 - 2*dot > 0: int-monotone after mask|idx pack
                const int p0 = (__float_as_int(dacc[0]) & ~511) | (mb + 0);
                const int p1 = (__float_as_int(dacc[1]) & ~511) | (mb + 1);
                const int p2 = (__float_as_int(dacc[2]) & ~511) | (mb + 2);
                const int p3 = (__float_as_int(dacc[3]) & ~511) | (mb + 3);
                int mn = min(p0, p1), mx = max(p0, p1);
                t2[s] = min(t2[s], max(min(t1[s], mx), mn));   // med3(t1,p0,p1)
                t1[s] = min(t1[s], mn);
                mn = min(p2, p3); mx = max(p2, p3);
                t2[s] = min(t2[s], max(min(t1[s], mx), mn));
                t1[s] = min(t1[s], mn);
            }
        }
        __syncthreads();   // all reads done before next stage overwrites
    }

    // ---- hand candidates to owning lane via LDS ----
    #pragma unroll
    for (int s = 0; s < 4; ++s) {
        cands[wv][s][cc][kl * 2 + 0] = t1[s];
        cands[wv][s][cc][kl * 2 + 1] = t2[s];
    }
    __syncthreads();

    const int tok = l0 + lane;           // lane owns token: strip = kl, col = cc
    int cd[8];
    #pragma unroll
    for (int j = 0; j < 8; ++j) cd[j] = cands[wv][kl][cc][j];
    int pmin = cd[0];
    #pragma unroll
    for (int j = 1; j < 8; ++j) pmin = min(pmin, cd[j]);

    // ---- reload this token's x column (fp32, coalesced, L2-hot) ----
    float xv[D_DIM];
    #pragma unroll
    for (int d = 0; d < D_DIM; ++d)
        xv[d] = xg[(size_t)d * L_SEQ + tok];

    // ---- exact fp32 rescore of near-minimal candidates (R6 single masked path) ----
    const float* __restrict__ eg  = emb + (size_t)n * M_CB * D_DIM;
    const float* __restrict__ e2g = e2raw + n * M_CB;
    float best1 = FLT_MAX, best2 = FLT_MAX;
    int   idx1  = 0x7FFFFFFF, idx2 = 0x7FFFFFFF;
    for (int j = 0; j < 8; ++j) {
        if (cd[j] - pmin <= MARGIN) {
            const int m = cd[j] & 511;
            const float4* em4 = reinterpret_cast<const float4*>(eg + (size_t)m * D_DIM);
            float a0 = 0.f, a1 = 0.f, a2 = 0.f, a3 = 0.f;
            #pragma unroll
            for (int q = 0; q < 16; ++q) {
                const float4 e4 = em4[q];
                a0 = fmaf(xv[q*4+0], e4.x, a0);
                a1 = fmaf(xv[q*4+1], e4.y, a1);
                a2 = fmaf(xv[q*4+2], e4.z, a2);
                a3 = fmaf(xv[q*4+3], e4.w, a3);
            }
            const float dist = fmaf(-2.f, (a0 + a1) + (a2 + a3), e2g[m]);
            if (dist < best1 || (dist == best1 && m < idx1)) {
                best2 = best1; idx2 = idx1; best1 = dist; idx1 = m;
            } else if (dist < best2 || (dist == best2 && m < idx2)) {
                best2 = dist; idx2 = m;
            }
        }
    }

    // ---- fp64 rescue for near-ties (validated semantics) ----
    if (best2 - best1 < 1e-4f) {
        const float* eA = eg + (size_t)idx1 * D_DIM;
        const float* eB = eg + (size_t)idx2 * D_DIM;
        double dA = 0.0, dB = 0.0;
        #pragma unroll
        for (int d = 0; d < D_DIM; ++d) {
            const double da = (double)xv[d] - (double)eA[d];
            const double db = (double)xv[d] - (double)eB[d];
            dA = fma(da, da, dA);
            dB = fma(db, db, dB);
        }
        if (dB < dA || (dB == dA && idx2 < idx1)) { idx1 = idx2; best1 = best2; }
    }

    // ---- epilogue: out = q; loss = Sum(x^2) + best dist; histogram ----
    const size_t obase = (size_t)(b * N_G + n) * D_DIM * L_SEQ + (size_t)tok;
    const float* __restrict__ ebest = eg + (size_t)idx1 * D_DIM;
    #pragma unroll
    for (int d = 0; d < D_DIM; d += 4) {
        const float4 qv = *reinterpret_cast<const float4*>(ebest + d);
        out[obase + (size_t)(d+0) * L_SEQ] = qv.x;
        out[obase + (size_t)(d+1) * L_SEQ] = qv.y;
        out[obase + (size_t)(d+2) * L_SEQ] = qv.z;
        out[obase + (size_t)(d+3) * L_SEQ] = qv.w;
    }

    float sq = x2p + best1;
    #pragma unroll
    for (int off = 32; off > 0; off >>= 1)
        sq += __shfl_down(sq, off, 64);
    if (lane == 0)
        atomicAdd(&lossAcc[bb & (NLOSS - 1)], sq);

    atomicAdd(&hist[idx1], 1);
    __syncthreads();
    {
        const int base = n * M_CB;
        int c0 = hist[tid];
        int c1 = hist[tid + 256];
        if (c0) atomicAdd(&counts[base + tid], c0);
        if (c1) atomicAdd(&counts[base + tid + 256], c1);
    }
}

__global__ void vq_finalize_kernel(const int* __restrict__ counts,
                                   const float* __restrict__ lossAcc,
                                   float* __restrict__ outTail) {
    __shared__ float red[256];
    const int tid = threadIdx.x;
    float perp = 0.f;
    for (int n = 0; n < N_G; ++n) {
        float h = 0.f;
        for (int m = tid; m < M_CB; m += 256) {
            const float p = (float)counts[n * M_CB + m] * (1.0f / (B_SZ * L_SEQ));
            h += p * logf(p + 1e-10f);
        }
        red[tid] = h;
        __syncthreads();
        #pragma unroll
        for (int s = 128; s > 0; s >>= 1) {
            if (tid < s) red[tid] += red[tid + s];
            __syncthreads();
        }
        if (tid == 0) perp += expf(-red[0]);
        __syncthreads();
    }
    if (tid == 0) {
        float ls = 0.f;
        for (int j = 0; j < NLOSS; ++j) ls += lossAcc[j];
        outTail[0] = 0.25f * (ls / (float)OUT_ELEMS);
        outTail[1] = perp;
    }
}

extern "C" void kernel_launch(void* const* d_in, const int* in_sizes, int n_in,
                              void* d_out, int out_size, void* d_ws, size_t ws_size,
                              hipStream_t stream) {
    const float* x   = (const float*)d_in[0];
    const float* emb = (const float*)d_in[1];
    float* out = (float*)d_out;
    char*  ws  = (char*)d_ws;

    unsigned int* ef16u  = (unsigned int*)(ws + EF_OFF);
    float* e2p    = (float*)(ws + E2P_OFF);
    float* e2r    = (float*)(ws + E2R_OFF);
    int*   counts = (int*)(ws + CNT_OFF);
    float* lossA  = (float*)(ws + LOSS_OFF);

    hipMemsetAsync(ws + CNT_OFF, 0, N_G * M_CB * 4 + NLOSS * 4, stream);
    vq_ef16_kernel<<<(N_G * M_CB * D_DIM / 2 + 255) / 256, 256, 0, stream>>>(emb, ef16u);
    vq_e2_kernel<<<(N_G * M_CB + 255) / 256, 256, 0, stream>>>(emb, e2r, e2p);
    vq_mfma_kernel<<<TOKENS / 256, 256, 0, stream>>>(
        x, emb, (const unsigned short*)ef16u, e2r, e2p, out, counts, lossA);
    vq_finalize_kernel<<<1, 256, 0, stream>>>(counts, lossA, out + OUT_ELEMS);
}